// Round 9
// baseline (811.665 us; speedup 1.0000x reference)
//
#include <hip/hip_runtime.h>
#include <hip/hip_bf16.h>

// out = (sum_k h[k] * S_k) @ x  — COO SpMM, bucket-binned, atomic-free accumulate.
//
// Round-8 lesson: scatter's per-WG cursor sub-ranges made (3126 streams x
// 128 WGs) = 400K write frontiers -> partial-line evictions (WRITE 221MB vs
// 64MB payload) at 0.84TB/s, with half the CUs idle (grid=128) and 633K LDS
// bank conflicts. Fix: ONE global atomic cursor per stream, padded to a
// 64B line (3126 frontiers total = 200KB, trivially L2-resident) -> full-
// line fills, any grid size, no LDS cursors, scan reduced to one pass.
// spmv gathers from a bf16 copy of x (round-8 win, 12.8MB, ~2x fewer bytes).
//
// Phases:
//   0) convert: x -> bf16 xh (12.8MB in ws)
//   A) count:   per-WG LDS histogram -> global atomicAdd into cntTot[s]
//   B) scan:    1-block exclusive scan -> ssBeg[s]; also seeds cursor lines
//   C) scatter: pos = atomicAdd(cursor[s*16]); payload[pos] = {rl<<17|col, w}
//   D) spmv:    block per 64-row bucket, wave per parity class, LDS f32 acc
//
// ws: cntTot[S] | ssBeg[S+1] | pad64 | cursor[S*16] | payload[KE] int2 | xh

#define RPB    64          // rows per bucket
#define SUB    2           // row classes (parity)
#define GWG_C  256         // count workgroups
#define GWG_S  1024        // scatter workgroups

static __global__ __launch_bounds__(1024) void count_kernel(
    const int* __restrict__ rows, int* __restrict__ cntTot,
    int KE, int NSTREAM, int chunk)
{
    extern __shared__ int hist[];              // NSTREAM ints
    const int g = blockIdx.x;
    for (int j = threadIdx.x; j < NSTREAM; j += blockDim.x) hist[j] = 0;
    __syncthreads();
    const int lo = g * chunk;
    const int hi = min(lo + chunk, KE);
    for (int e = lo + threadIdx.x; e < hi; e += blockDim.x) {
        const int r = rows[e];
        atomicAdd(&hist[((r >> 6) << 1) | (r & 1)], 1);
    }
    __syncthreads();
    for (int j = threadIdx.x; j < NSTREAM; j += blockDim.x) {
        const int v = hist[j];
        if (v) atomicAdd(&cntTot[j], v);
    }
}

// exclusive scan of cntTot[0..n) -> ssBeg[0..n], ssBeg[n]=total;
// also seeds the padded global cursors: cursor[i*16] = ssBeg[i]
static __global__ __launch_bounds__(1024) void scan_kernel(
    const int* __restrict__ cntTot, int* __restrict__ ssBeg,
    int* __restrict__ cursor, int n)
{
    __shared__ int sums[1024];
    const int t = threadIdx.x;
    const int chunk = (n + 1023) >> 10;
    const int lo = t * chunk;
    const int hi = min(lo + chunk, n);
    int s = 0;
    for (int i = lo; i < hi; ++i) s += cntTot[i];
    sums[t] = s;
    __syncthreads();
    for (int d = 1; d < 1024; d <<= 1) {
        int v = (t >= d) ? sums[t - d] : 0;
        __syncthreads();
        sums[t] += v;
        __syncthreads();
    }
    int run = (t > 0) ? sums[t - 1] : 0;
    for (int i = lo; i < hi; ++i) {
        const int cv = cntTot[i];
        ssBeg[i] = run;
        cursor[(size_t)i * 16] = run;
        run += cv;
    }
    if (t == 1023) ssBeg[n] = sums[1023];
}

static __global__ __launch_bounds__(256) void scatter_kernel(
    const int*   __restrict__ rows,
    const int*   __restrict__ cols,
    const float* __restrict__ vals,
    const float* __restrict__ h,
    int*         __restrict__ cursor,       // padded: stream s at [s*16]
    int2*        __restrict__ payload,
    int KE, int E, int K, int chunk)
{
    const int g = blockIdx.x;
    const int lo = g * chunk;
    const int hi = min(lo + chunk, KE);
    if (lo >= hi) return;
    const int k0 = lo / E;
    const int k1 = min((hi - 1) / E, K - 1);
    for (int k = k0; k <= k1; ++k) {
        const float hk = h[k];
        const int s0 = max(lo, k * E);
        const int s1 = min(hi, (k + 1) * E);
        for (int e = s0 + threadIdx.x; e < s1; e += blockDim.x) {
            const int r = rows[e];
            const int st = ((r >> 6) << 1) | (r & 1);
            const int pos = atomicAdd(&cursor[(size_t)st * 16], 1);
            payload[pos] = make_int2(((r & 63) << 17) | cols[e],
                                     __float_as_int(hk * vals[e]));
        }
    }
}

// x (f32) -> xh (bf16), vectorized: float4 in, ushort4 out
static __global__ __launch_bounds__(256) void convert_kernel(
    const float* __restrict__ x, ushort* __restrict__ xh, int n4)
{
    const int i = blockIdx.x * blockDim.x + threadIdx.x;
    if (i >= n4) return;
    const float4 v = ((const float4*)x)[i];
    ushort4 o;
    o.x = __bfloat16_as_ushort(__float2bfloat16(v.x));
    o.y = __bfloat16_as_ushort(__float2bfloat16(v.y));
    o.z = __bfloat16_as_ushort(__float2bfloat16(v.z));
    o.w = __bfloat16_as_ushort(__float2bfloat16(v.w));
    ((ushort4*)xh)[i] = o;
}

static __global__ __launch_bounds__(128) void spmv_bf16_kernel(
    const int*    __restrict__ ssBeg,
    const int2*   __restrict__ payload,
    const ushort* __restrict__ xh,
    float*        __restrict__ out,
    int N)
{
    __shared__ float acc[RPB * 64];            // 16KB
    const int b = blockIdx.x;
    for (int i = threadIdx.x; i < RPB * 64; i += 128) acc[i] = 0.f;
    __syncthreads();

    const int lane = threadIdx.x & 63;
    const int wv   = threadIdx.x >> 6;         // 0..1, owns rows r%2==wv
    const int s    = b * SUB + wv;
    int e        = ssBeg[s];
    const int be = ssBeg[s + 1];

    while (e + 16 <= be) {
        int2 pa[8], pb[8];
        float xa[8], xb[8];
        #pragma unroll
        for (int j = 0; j < 8; ++j) pa[j] = payload[e + j];
        #pragma unroll
        for (int j = 0; j < 8; ++j) pb[j] = payload[e + 8 + j];
        #pragma unroll
        for (int j = 0; j < 8; ++j)
            xa[j] = __bfloat162float(__ushort_as_bfloat16(
                        xh[(size_t)(pa[j].x & 0x1FFFF) * 64 + lane]));
        #pragma unroll
        for (int j = 0; j < 8; ++j)
            xb[j] = __bfloat162float(__ushort_as_bfloat16(
                        xh[(size_t)(pb[j].x & 0x1FFFF) * 64 + lane]));
        #pragma unroll
        for (int j = 0; j < 8; ++j)
            acc[(pa[j].x >> 17) * 64 + lane] += __int_as_float(pa[j].y) * xa[j];
        #pragma unroll
        for (int j = 0; j < 8; ++j)
            acc[(pb[j].x >> 17) * 64 + lane] += __int_as_float(pb[j].y) * xb[j];
        e += 16;
    }
    for (; e < be; ++e) {
        const int2 p = payload[e];
        const float xv = __bfloat162float(__ushort_as_bfloat16(
                             xh[(size_t)(p.x & 0x1FFFF) * 64 + lane]));
        acc[(p.x >> 17) * 64 + lane] += __int_as_float(p.y) * xv;
    }
    __syncthreads();

    const int base = b * RPB;
    const int nrow = min(RPB, N - base);
    for (int i = threadIdx.x; i < nrow * 64; i += 128)
        out[(size_t)base * 64 + i] = acc[i];
}

// f32-gather variant — used if ws can't hold the bf16 copy.
static __global__ __launch_bounds__(128) void spmv_f32_kernel(
    const int*  __restrict__ ssBeg,
    const int2* __restrict__ payload,
    const float* __restrict__ x,
    float*       __restrict__ out,
    int N)
{
    __shared__ float acc[RPB * 64];
    const int b = blockIdx.x;
    for (int i = threadIdx.x; i < RPB * 64; i += 128) acc[i] = 0.f;
    __syncthreads();

    const int lane = threadIdx.x & 63;
    const int wv   = threadIdx.x >> 6;
    const int s    = b * SUB + wv;
    int e        = ssBeg[s];
    const int be = ssBeg[s + 1];

    while (e + 16 <= be) {
        int2 pa[8], pb[8];
        float xa[8], xb[8];
        #pragma unroll
        for (int j = 0; j < 8; ++j) pa[j] = payload[e + j];
        #pragma unroll
        for (int j = 0; j < 8; ++j) pb[j] = payload[e + 8 + j];
        #pragma unroll
        for (int j = 0; j < 8; ++j)
            xa[j] = x[(size_t)(pa[j].x & 0x1FFFF) * 64 + lane];
        #pragma unroll
        for (int j = 0; j < 8; ++j)
            xb[j] = x[(size_t)(pb[j].x & 0x1FFFF) * 64 + lane];
        #pragma unroll
        for (int j = 0; j < 8; ++j)
            acc[(pa[j].x >> 17) * 64 + lane] += __int_as_float(pa[j].y) * xa[j];
        #pragma unroll
        for (int j = 0; j < 8; ++j)
            acc[(pb[j].x >> 17) * 64 + lane] += __int_as_float(pb[j].y) * xb[j];
        e += 16;
    }
    for (; e < be; ++e) {
        const int2 p = payload[e];
        acc[(p.x >> 17) * 64 + lane] +=
            __int_as_float(p.y) * x[(size_t)(p.x & 0x1FFFF) * 64 + lane];
    }
    __syncthreads();

    const int base = b * RPB;
    const int nrow = min(RPB, N - base);
    for (int i = threadIdx.x; i < nrow * 64; i += 128)
        out[(size_t)base * 64 + i] = acc[i];
}

// Round-1 fallback (atomic scatter) if ws is too small for binning at all.
static __global__ __launch_bounds__(256) void gtconv_scatter(
    const float* __restrict__ x, const float* __restrict__ h,
    const float* __restrict__ vals, const int* __restrict__ rows,
    const int* __restrict__ cols, float* __restrict__ out, int KE, int E)
{
    const int lane = threadIdx.x & 63;
    int wave = (blockIdx.x * blockDim.x + threadIdx.x) >> 6;
    const int nwaves = (gridDim.x * blockDim.x) >> 6;
    for (int e = wave; e < KE; e += nwaves) {
        float w = h[e / E] * vals[e];
        float xv = x[(size_t)cols[e] * 64 + lane];
        unsafeAtomicAdd(&out[(size_t)rows[e] * 64 + lane], xv * w);
    }
}

extern "C" void kernel_launch(void* const* d_in, const int* in_sizes, int n_in,
                              void* d_out, int out_size, void* d_ws, size_t ws_size,
                              hipStream_t stream) {
    const float* x    = (const float*)d_in[0];
    const float* h    = (const float*)d_in[1];
    const float* vals = (const float*)d_in[2];
    const int*   rows = (const int*)d_in[3];
    const int*   cols = (const int*)d_in[4];
    float* out = (float*)d_out;

    const int K  = in_sizes[1];
    const int KE = in_sizes[2];
    const int E  = KE / K;
    const int F  = 64;
    const int N  = in_sizes[0] / F;
    const int NB      = (N + RPB - 1) / RPB;       // 1563
    const int NSTREAM = NB * SUB;                  // 3126

    const size_t lds_need  = (size_t)NSTREAM * 4;  // count LDS (12.5KB)
    const size_t ct_off    = 0;
    const size_t ss_off    = ct_off + (size_t)NSTREAM * 4;
    const size_t cur_off   = (ss_off + (size_t)(NSTREAM + 1) * 4 + 63) & ~(size_t)63;
    const size_t pl_off    = (cur_off + (size_t)NSTREAM * 64 + 15) & ~(size_t)15;
    const size_t base_need = pl_off + (size_t)KE * 8;
    const size_t xh_off    = (base_need + 15) & ~(size_t)15;
    const size_t full_need = xh_off + (size_t)N * F * 2;

    if (ws_size < base_need || lds_need > 64 * 1024) {
        hipMemsetAsync(out, 0, (size_t)out_size * sizeof(float), stream);
        gtconv_scatter<<<8192, 256, 0, stream>>>(x, h, vals, rows, cols, out, KE, E);
        return;
    }

    char* ws = (char*)d_ws;
    int*    cntTot  = (int*)(ws + ct_off);
    int*    ssBeg   = (int*)(ws + ss_off);
    int*    cursor  = (int*)(ws + cur_off);      // stream s at cursor[s*16]
    int2*   payload = (int2*)(ws + pl_off);
    ushort* xh      = (ushort*)(ws + xh_off);
    const bool use_bf16 = (ws_size >= full_need);

    hipMemsetAsync(cntTot, 0, (size_t)NSTREAM * 4, stream);
    if (use_bf16) {
        const int n4 = (N * F) / 4;
        convert_kernel<<<(n4 + 255) / 256, 256, 0, stream>>>(x, xh, n4);
    }

    const int chunk_c = (KE + GWG_C - 1) / GWG_C;
    count_kernel<<<GWG_C, 1024, lds_need, stream>>>(rows, cntTot, KE, NSTREAM, chunk_c);
    scan_kernel<<<1, 1024, 0, stream>>>(cntTot, ssBeg, cursor, NSTREAM);
    const int chunk_s = (KE + GWG_S - 1) / GWG_S;
    scatter_kernel<<<GWG_S, 256, 0, stream>>>(rows, cols, vals, h, cursor,
                                              payload, KE, E, K, chunk_s);
    if (use_bf16)
        spmv_bf16_kernel<<<NB, 128, 0, stream>>>(ssBeg, payload, xh, out, N);
    else
        spmv_f32_kernel<<<NB, 128, 0, stream>>>(ssBeg, payload, x, out, N);
}

// Round 10
// 722.044 us; speedup vs baseline: 1.1241x; 1.1241x over previous
//
#include <hip/hip_runtime.h>
#include <hip/hip_bf16.h>

// out = (sum_k h[k] * S_k) @ x  — COO SpMM, bucket-binned, atomic-free accumulate.
//
// Round-9 lesson: ONE shared cursor per stream made every frontier line
// writable by all 8 XCDs -> coherence ping-pong, WRITE 458MB (~7x payload).
// Round-8 lesson: per-WG ranges -> 400K frontiers -> capacity evictions.
// Fix: NPART=8 partitions keyed by scatter-WG id (g&7). Under round-robin
// dispatch blockIdx%8 == XCD, so each partition's frontier lines are
// XCD-PRIVATE (correctness never depends on this — partitions are disjoint
// by construction). 25K frontiers total, ~400KB/XCD. Cursors & count bins
// partition-major + 64B-aligned so their lines are XCD-private too.
// s-major scan order keeps each stream's 8 partitions CONTIGUOUS in
// payload -> spmv just reads stream bounds at stride 8.
// Payload = pidx(int) + pw(bf16) = 6B/edge; x gathered as bf16 (round-8 win).
//
// ws: cnt[8][PS] | cur[8][PS] | ssBeg8[S*8+1] | pidx[KE] | pw[KE] | xh[N*64]

#define RPB    64          // rows per bucket
#define SUB    2           // row classes (parity)
#define NPART  8           // writer partitions (~XCDs)
#define GWG    1024        // count/scatter workgroups

static __global__ __launch_bounds__(1024) void count_kernel(
    const int* __restrict__ rows, int* __restrict__ cnt,
    int KE, int NSTREAM, int PS, int chunk)
{
    extern __shared__ int hist[];              // NSTREAM ints
    const int g = blockIdx.x;
    const int p = g & (NPART - 1);
    for (int j = threadIdx.x; j < NSTREAM; j += blockDim.x) hist[j] = 0;
    __syncthreads();
    const int lo = g * chunk;
    const int hi = min(lo + chunk, KE);
    for (int e = lo + threadIdx.x; e < hi; e += blockDim.x) {
        const int r = rows[e];
        atomicAdd(&hist[((r >> 6) << 1) | (r & 1)], 1);
    }
    __syncthreads();
    for (int j = threadIdx.x; j < NSTREAM; j += blockDim.x) {
        const int v = hist[j];
        if (v) atomicAdd(&cnt[p * PS + j], v);
    }
}

// exclusive scan over logical (s,p) s-major order; seeds cursors.
// ssBeg8[s*8+p] = start of stream s / partition p; ssBeg8[S*8] = total.
static __global__ __launch_bounds__(1024) void scan_kernel(
    const int* __restrict__ cnt, int* __restrict__ ssBeg8,
    int* __restrict__ cur, int NSTREAM, int PS)
{
    __shared__ int sums[1024];
    const int n = NSTREAM * NPART;
    const int t = threadIdx.x;
    const int chunk = (n + 1023) >> 10;
    const int lo = t * chunk;
    const int hi = min(lo + chunk, n);
    int s = 0;
    for (int i = lo; i < hi; ++i)
        s += cnt[(i & (NPART - 1)) * PS + (i >> 3)];
    sums[t] = s;
    __syncthreads();
    for (int d = 1; d < 1024; d <<= 1) {
        int v = (t >= d) ? sums[t - d] : 0;
        __syncthreads();
        sums[t] += v;
        __syncthreads();
    }
    int run = (t > 0) ? sums[t - 1] : 0;
    for (int i = lo; i < hi; ++i) {
        const int phys = (i & (NPART - 1)) * PS + (i >> 3);
        const int cv = cnt[phys];
        ssBeg8[i] = run;
        cur[phys] = run;
        run += cv;
    }
    if (t == 1023) ssBeg8[n] = sums[1023];
}

static __global__ __launch_bounds__(256) void scatter_kernel(
    const int*   __restrict__ rows,
    const int*   __restrict__ cols,
    const float* __restrict__ vals,
    const float* __restrict__ h,
    int*         __restrict__ cur,          // [p*PS + s], XCD-private blocks
    int*         __restrict__ pidx,
    ushort*      __restrict__ pw,
    int KE, int E, int K, int PS, int chunk)
{
    const int g = blockIdx.x;
    const int p = g & (NPART - 1);
    int* mycur = cur + (size_t)p * PS;
    const int lo = g * chunk;
    const int hi = min(lo + chunk, KE);
    if (lo >= hi) return;
    const int k0 = lo / E;
    const int k1 = min((hi - 1) / E, K - 1);
    for (int k = k0; k <= k1; ++k) {
        const float hk = h[k];
        const int s0 = max(lo, k * E);
        const int s1 = min(hi, (k + 1) * E);
        for (int e = s0 + threadIdx.x; e < s1; e += blockDim.x) {
            const int r = rows[e];
            const int st = ((r >> 6) << 1) | (r & 1);
            const int pos = atomicAdd(&mycur[st], 1);
            pidx[pos] = ((r & 63) << 17) | cols[e];
            pw[pos] = __bfloat16_as_ushort(__float2bfloat16(hk * vals[e]));
        }
    }
}

// x (f32) -> xh (bf16), vectorized: float4 in, ushort4 out
static __global__ __launch_bounds__(256) void convert_kernel(
    const float* __restrict__ x, ushort* __restrict__ xh, int n4)
{
    const int i = blockIdx.x * blockDim.x + threadIdx.x;
    if (i >= n4) return;
    const float4 v = ((const float4*)x)[i];
    ushort4 o;
    o.x = __bfloat16_as_ushort(__float2bfloat16(v.x));
    o.y = __bfloat16_as_ushort(__float2bfloat16(v.y));
    o.z = __bfloat16_as_ushort(__float2bfloat16(v.z));
    o.w = __bfloat16_as_ushort(__float2bfloat16(v.w));
    ((ushort4*)xh)[i] = o;
}

static __global__ __launch_bounds__(128) void spmv_kernel(
    const int*    __restrict__ ssBeg8,
    const int*    __restrict__ pidx,
    const ushort* __restrict__ pw,
    const ushort* __restrict__ xh,
    float*        __restrict__ out,
    int N)
{
    __shared__ float acc[RPB * 64];            // 16KB
    const int b = blockIdx.x;
    for (int i = threadIdx.x; i < RPB * 64; i += 128) acc[i] = 0.f;
    __syncthreads();

    const int lane = threadIdx.x & 63;
    const int wv   = threadIdx.x >> 6;         // 0..1, owns rows r%2==wv
    const int s    = b * SUB + wv;
    int e        = ssBeg8[(size_t)s * NPART];          // stream start
    const int be = ssBeg8[(size_t)(s + 1) * NPART];    // stream end (contig!)

    while (e + 16 <= be) {
        int ia[8], ib[8];
        ushort wa[8], wb[8];
        float xa[8], xb[8];
        #pragma unroll
        for (int j = 0; j < 8; ++j) { ia[j] = pidx[e + j]; wa[j] = pw[e + j]; }
        #pragma unroll
        for (int j = 0; j < 8; ++j) { ib[j] = pidx[e + 8 + j]; wb[j] = pw[e + 8 + j]; }
        #pragma unroll
        for (int j = 0; j < 8; ++j)
            xa[j] = __bfloat162float(__ushort_as_bfloat16(
                        xh[(size_t)(ia[j] & 0x1FFFF) * 64 + lane]));
        #pragma unroll
        for (int j = 0; j < 8; ++j)
            xb[j] = __bfloat162float(__ushort_as_bfloat16(
                        xh[(size_t)(ib[j] & 0x1FFFF) * 64 + lane]));
        #pragma unroll
        for (int j = 0; j < 8; ++j)
            acc[(ia[j] >> 17) * 64 + lane] +=
                __bfloat162float(__ushort_as_bfloat16(wa[j])) * xa[j];
        #pragma unroll
        for (int j = 0; j < 8; ++j)
            acc[(ib[j] >> 17) * 64 + lane] +=
                __bfloat162float(__ushort_as_bfloat16(wb[j])) * xb[j];
        e += 16;
    }
    for (; e < be; ++e) {
        const int i_ = pidx[e];
        const float xv = __bfloat162float(__ushort_as_bfloat16(
                             xh[(size_t)(i_ & 0x1FFFF) * 64 + lane]));
        acc[(i_ >> 17) * 64 + lane] +=
            __bfloat162float(__ushort_as_bfloat16(pw[e])) * xv;
    }
    __syncthreads();

    const int base = b * RPB;
    const int nrow = min(RPB, N - base);
    for (int i = threadIdx.x; i < nrow * 64; i += 128)
        out[(size_t)base * 64 + i] = acc[i];
}

// Round-1 fallback (atomic scatter) if ws is too small.
static __global__ __launch_bounds__(256) void gtconv_scatter(
    const float* __restrict__ x, const float* __restrict__ h,
    const float* __restrict__ vals, const int* __restrict__ rows,
    const int* __restrict__ cols, float* __restrict__ out, int KE, int E)
{
    const int lane = threadIdx.x & 63;
    int wave = (blockIdx.x * blockDim.x + threadIdx.x) >> 6;
    const int nwaves = (gridDim.x * blockDim.x) >> 6;
    for (int e = wave; e < KE; e += nwaves) {
        float w = h[e / E] * vals[e];
        float xv = x[(size_t)cols[e] * 64 + lane];
        unsafeAtomicAdd(&out[(size_t)rows[e] * 64 + lane], xv * w);
    }
}

extern "C" void kernel_launch(void* const* d_in, const int* in_sizes, int n_in,
                              void* d_out, int out_size, void* d_ws, size_t ws_size,
                              hipStream_t stream) {
    const float* x    = (const float*)d_in[0];
    const float* h    = (const float*)d_in[1];
    const float* vals = (const float*)d_in[2];
    const int*   rows = (const int*)d_in[3];
    const int*   cols = (const int*)d_in[4];
    float* out = (float*)d_out;

    const int K  = in_sizes[1];
    const int KE = in_sizes[2];
    const int E  = KE / K;
    const int F  = 64;
    const int N  = in_sizes[0] / F;
    const int NB      = (N + RPB - 1) / RPB;       // 1563
    const int NSTREAM = NB * SUB;                  // 3126
    const int PS      = (NSTREAM + 15) & ~15;      // 3136: 64B-aligned blocks

    const size_t lds_need = (size_t)NSTREAM * 4;   // count LDS (12.5KB)
    const size_t cnt_off  = 0;
    const size_t cnt_sz   = (size_t)NPART * PS * 4;
    const size_t cur_off  = cnt_off + cnt_sz;
    const size_t ss_off   = cur_off + cnt_sz;
    const size_t ss_sz    = ((size_t)NSTREAM * NPART + 1) * 4;
    const size_t pi_off   = (ss_off + ss_sz + 63) & ~(size_t)63;
    const size_t pw_off   = pi_off + (size_t)KE * 4;
    const size_t xh_off   = (pw_off + (size_t)KE * 2 + 63) & ~(size_t)63;
    const size_t need     = xh_off + (size_t)N * F * 2;

    if (ws_size < need || lds_need > 64 * 1024) {
        hipMemsetAsync(out, 0, (size_t)out_size * sizeof(float), stream);
        gtconv_scatter<<<8192, 256, 0, stream>>>(x, h, vals, rows, cols, out, KE, E);
        return;
    }

    char* ws = (char*)d_ws;
    int*    cnt    = (int*)(ws + cnt_off);
    int*    cur    = (int*)(ws + cur_off);
    int*    ssBeg8 = (int*)(ws + ss_off);
    int*    pidx   = (int*)(ws + pi_off);
    ushort* pw     = (ushort*)(ws + pw_off);
    ushort* xh     = (ushort*)(ws + xh_off);

    hipMemsetAsync(cnt, 0, cnt_sz, stream);
    const int n4 = (N * F) / 4;
    convert_kernel<<<(n4 + 255) / 256, 256, 0, stream>>>(x, xh, n4);

    const int chunk = (KE + GWG - 1) / GWG;
    count_kernel<<<GWG, 1024, lds_need, stream>>>(rows, cnt, KE, NSTREAM, PS, chunk);
    scan_kernel<<<1, 1024, 0, stream>>>(cnt, ssBeg8, cur, NSTREAM, PS);
    scatter_kernel<<<GWG, 256, 0, stream>>>(rows, cols, vals, h, cur,
                                            pidx, pw, KE, E, K, PS, chunk);
    spmv_kernel<<<NB, 128, 0, stream>>>(ssBeg8, pidx, pw, xh, out, N);
}

// Round 11
// 384.199 us; speedup vs baseline: 2.1126x; 1.8793x over previous
//
#include <hip/hip_runtime.h>
#include <hip/hip_bf16.h>

// out = (sum_k h[k] * S_k) @ x  — COO SpMM, bucket-binned, atomic-free accumulate.
//
// Round-11 synthesis of the two proven wins:
//  * r5 scatter (per-WG cursor ranges, GWG=128, 3126 streams, single int2
//    8B payload): frontier lines = 3126 x 16 WGs/XCD x 64B = 3.2MB <= 4MB
//    per-XCD L2 -> full-line fills, ~60us. (r8's 6B SPLIT payload doubled
//    frontier bytes -> 6.4MB -> thrash, 270us. r9/r10 shared-cursor variants
//    ping-ponged lines across XCDs: 458/307MB writes.)
//  * r8 spmv gather from bf16 copy of x (12.8MB): halves gather line traffic.
// Everything else r5-verbatim. Tier B (ws too small for xh): r5 f32 gather.
//
// ws: cnt[NSTREAM*GWG] | ssBeg[NSTREAM+1] | pad | payload[KE] int2 | xh[N*64] bf16

#define RPB   64           // rows per bucket
#define SUB   2            // row classes (parity)
#define GWG   128          // count/scatter workgroups

static __global__ __launch_bounds__(1024) void count_kernel(
    const int* __restrict__ rows, int* __restrict__ cnt,
    int KE, int NSTREAM, int chunk)
{
    extern __shared__ int hist[];              // NSTREAM ints
    const int g = blockIdx.x;
    for (int j = threadIdx.x; j < NSTREAM; j += blockDim.x) hist[j] = 0;
    __syncthreads();
    const int lo = g * chunk;
    const int hi = min(lo + chunk, KE);
    for (int e = lo + threadIdx.x; e < hi; e += blockDim.x) {
        const int r = rows[e];
        atomicAdd(&hist[((r >> 6) << 1) | (r & 1)], 1);
    }
    __syncthreads();
    for (int j = threadIdx.x; j < NSTREAM; j += blockDim.x)
        cnt[(size_t)j * GWG + g] = hist[j];
}

// B1: per-stream exclusive scan of its GWG counts (in place); total -> ssBeg[s]
static __global__ __launch_bounds__(GWG) void scan1_kernel(
    int* __restrict__ cnt, int* __restrict__ ssBeg)
{
    __shared__ int tmp[GWG];
    const int s = blockIdx.x;
    const int t = threadIdx.x;
    const int v = cnt[(size_t)s * GWG + t];
    tmp[t] = v;
    __syncthreads();
    for (int d = 1; d < GWG; d <<= 1) {
        int u = (t >= d) ? tmp[t - d] : 0;
        __syncthreads();
        tmp[t] += u;
        __syncthreads();
    }
    cnt[(size_t)s * GWG + t] = tmp[t] - v;     // exclusive
    if (t == GWG - 1) ssBeg[s] = tmp[t];       // stream total
}

// B2: exclusive scan of ssBeg[0..n) in place; ssBeg[n] = grand total
static __global__ __launch_bounds__(1024) void scan2_kernel(
    int* __restrict__ a, int n)
{
    __shared__ int sums[1024];
    const int t = threadIdx.x;
    const int chunk = (n + 1023) >> 10;
    const int lo = t * chunk;
    const int hi = min(lo + chunk, n);
    int s = 0;
    for (int i = lo; i < hi; ++i) s += a[i];
    sums[t] = s;
    __syncthreads();
    for (int d = 1; d < 1024; d <<= 1) {
        int v = (t >= d) ? sums[t - d] : 0;
        __syncthreads();
        sums[t] += v;
        __syncthreads();
    }
    int run = (t > 0) ? sums[t - 1] : 0;
    for (int i = lo; i < hi; ++i) {
        const int cv = a[i];
        a[i] = run;
        run += cv;
    }
    if (t == 1023) a[n] = sums[1023];
}

// B3: cnt[s][g] += stream base
static __global__ __launch_bounds__(1024) void scan3_kernel(
    int* __restrict__ cnt, const int* __restrict__ ssBeg, int total)
{
    const int i = blockIdx.x * blockDim.x + threadIdx.x;
    if (i < total) cnt[i] += ssBeg[i >> 7];    // i / GWG (GWG=128)
}

static __global__ __launch_bounds__(1024) void scatter_kernel(
    const int*   __restrict__ rows,
    const int*   __restrict__ cols,
    const float* __restrict__ vals,
    const float* __restrict__ h,
    const int*   __restrict__ cnt,
    int2*        __restrict__ payload,
    int KE, int E, int K, int NSTREAM, int chunk)
{
    extern __shared__ int lcur[];              // NSTREAM cursors
    const int g = blockIdx.x;
    for (int j = threadIdx.x; j < NSTREAM; j += blockDim.x)
        lcur[j] = cnt[(size_t)j * GWG + g];
    __syncthreads();
    const int lo = g * chunk;
    const int hi = min(lo + chunk, KE);
    if (lo >= hi) return;
    const int k0 = lo / E;
    const int k1 = min((hi - 1) / E, K - 1);
    for (int k = k0; k <= k1; ++k) {
        const float hk = h[k];
        const int s0 = max(lo, k * E);
        const int s1 = min(hi, (k + 1) * E);
        for (int e = s0 + threadIdx.x; e < s1; e += blockDim.x) {
            const int r = rows[e];
            const int st = ((r >> 6) << 1) | (r & 1);
            const int pos = atomicAdd(&lcur[st], 1);      // int LDS atomic
            payload[pos] = make_int2(((r & 63) << 17) | cols[e],
                                     __float_as_int(hk * vals[e]));
        }
    }
}

// x (f32) -> xh (bf16), vectorized: float4 in, ushort4 out
static __global__ __launch_bounds__(256) void convert_kernel(
    const float* __restrict__ x, ushort* __restrict__ xh, int n4)
{
    const int i = blockIdx.x * blockDim.x + threadIdx.x;
    if (i >= n4) return;
    const float4 v = ((const float4*)x)[i];
    ushort4 o;
    o.x = __bfloat16_as_ushort(__float2bfloat16(v.x));
    o.y = __bfloat16_as_ushort(__float2bfloat16(v.y));
    o.z = __bfloat16_as_ushort(__float2bfloat16(v.z));
    o.w = __bfloat16_as_ushort(__float2bfloat16(v.w));
    ((ushort4*)xh)[i] = o;
}

// Tier A: r5 spmv structure, gathers from bf16 xh (the only change vs r5).
static __global__ __launch_bounds__(128) void spmv_bf16_kernel(
    const int*    __restrict__ ssBeg,
    const int2*   __restrict__ payload,
    const ushort* __restrict__ xh,
    float*        __restrict__ out,
    int N)
{
    __shared__ float acc[RPB * 64];            // 16KB
    const int b = blockIdx.x;
    for (int i = threadIdx.x; i < RPB * 64; i += 128) acc[i] = 0.f;
    __syncthreads();

    const int lane = threadIdx.x & 63;
    const int wv   = threadIdx.x >> 6;         // 0..1, owns rows r%2==wv
    const int s    = b * SUB + wv;
    int e        = ssBeg[s];
    const int be = ssBeg[s + 1];

    while (e + 16 <= be) {
        int2 pa[8], pb[8];
        float xa[8], xb[8];
        #pragma unroll
        for (int j = 0; j < 8; ++j) pa[j] = payload[e + j];
        #pragma unroll
        for (int j = 0; j < 8; ++j) pb[j] = payload[e + 8 + j];
        #pragma unroll
        for (int j = 0; j < 8; ++j)
            xa[j] = __bfloat162float(__ushort_as_bfloat16(
                        xh[(size_t)(pa[j].x & 0x1FFFF) * 64 + lane]));
        #pragma unroll
        for (int j = 0; j < 8; ++j)
            xb[j] = __bfloat162float(__ushort_as_bfloat16(
                        xh[(size_t)(pb[j].x & 0x1FFFF) * 64 + lane]));
        #pragma unroll
        for (int j = 0; j < 8; ++j)
            acc[(pa[j].x >> 17) * 64 + lane] += __int_as_float(pa[j].y) * xa[j];
        #pragma unroll
        for (int j = 0; j < 8; ++j)
            acc[(pb[j].x >> 17) * 64 + lane] += __int_as_float(pb[j].y) * xb[j];
        e += 16;
    }
    for (; e < be; ++e) {
        const int2 p = payload[e];
        const float xv = __bfloat162float(__ushort_as_bfloat16(
                             xh[(size_t)(p.x & 0x1FFFF) * 64 + lane]));
        acc[(p.x >> 17) * 64 + lane] += __int_as_float(p.y) * xv;
    }
    __syncthreads();

    const int base = b * RPB;
    const int nrow = min(RPB, N - base);
    for (int i = threadIdx.x; i < nrow * 64; i += 128)
        out[(size_t)base * 64 + i] = acc[i];
}

// Tier B: r5 spmv verbatim (f32 gather) if ws can't hold xh.
static __global__ __launch_bounds__(128) void spmv_f32_kernel(
    const int*  __restrict__ ssBeg,
    const int2* __restrict__ payload,
    const float* __restrict__ x,
    float*       __restrict__ out,
    int N)
{
    __shared__ float acc[RPB * 64];
    const int b = blockIdx.x;
    for (int i = threadIdx.x; i < RPB * 64; i += 128) acc[i] = 0.f;
    __syncthreads();

    const int lane = threadIdx.x & 63;
    const int wv   = threadIdx.x >> 6;
    const int s    = b * SUB + wv;
    int e        = ssBeg[s];
    const int be = ssBeg[s + 1];

    while (e + 16 <= be) {
        int2 pa[8], pb[8];
        float xa[8], xb[8];
        #pragma unroll
        for (int j = 0; j < 8; ++j) pa[j] = payload[e + j];
        #pragma unroll
        for (int j = 0; j < 8; ++j) pb[j] = payload[e + 8 + j];
        #pragma unroll
        for (int j = 0; j < 8; ++j)
            xa[j] = x[(size_t)(pa[j].x & 0x1FFFF) * 64 + lane];
        #pragma unroll
        for (int j = 0; j < 8; ++j)
            xb[j] = x[(size_t)(pb[j].x & 0x1FFFF) * 64 + lane];
        #pragma unroll
        for (int j = 0; j < 8; ++j)
            acc[(pa[j].x >> 17) * 64 + lane] += __int_as_float(pa[j].y) * xa[j];
        #pragma unroll
        for (int j = 0; j < 8; ++j)
            acc[(pb[j].x >> 17) * 64 + lane] += __int_as_float(pb[j].y) * xb[j];
        e += 16;
    }
    for (; e < be; ++e) {
        const int2 p = payload[e];
        acc[(p.x >> 17) * 64 + lane] +=
            __int_as_float(p.y) * x[(size_t)(p.x & 0x1FFFF) * 64 + lane];
    }
    __syncthreads();

    const int base = b * RPB;
    const int nrow = min(RPB, N - base);
    for (int i = threadIdx.x; i < nrow * 64; i += 128)
        out[(size_t)base * 64 + i] = acc[i];
}

// Round-1 fallback (atomic scatter) if ws is too small for binning at all.
static __global__ __launch_bounds__(256) void gtconv_scatter(
    const float* __restrict__ x, const float* __restrict__ h,
    const float* __restrict__ vals, const int* __restrict__ rows,
    const int* __restrict__ cols, float* __restrict__ out, int KE, int E)
{
    const int lane = threadIdx.x & 63;
    int wave = (blockIdx.x * blockDim.x + threadIdx.x) >> 6;
    const int nwaves = (gridDim.x * blockDim.x) >> 6;
    for (int e = wave; e < KE; e += nwaves) {
        float w = h[e / E] * vals[e];
        float xv = x[(size_t)cols[e] * 64 + lane];
        unsafeAtomicAdd(&out[(size_t)rows[e] * 64 + lane], xv * w);
    }
}

extern "C" void kernel_launch(void* const* d_in, const int* in_sizes, int n_in,
                              void* d_out, int out_size, void* d_ws, size_t ws_size,
                              hipStream_t stream) {
    const float* x    = (const float*)d_in[0];
    const float* h    = (const float*)d_in[1];
    const float* vals = (const float*)d_in[2];
    const int*   rows = (const int*)d_in[3];
    const int*   cols = (const int*)d_in[4];
    float* out = (float*)d_out;

    const int K  = in_sizes[1];
    const int KE = in_sizes[2];
    const int E  = KE / K;
    const int F  = 64;
    const int N  = in_sizes[0] / F;
    const int NB      = (N + RPB - 1) / RPB;       // 1563
    const int NSTREAM = NB * SUB;                  // 3126

    const size_t lds_need = (size_t)NSTREAM * 4;   // count/scatter LDS
    const size_t cnt_off  = 0;
    const size_t cnt_sz   = (size_t)NSTREAM * GWG * 4;
    const size_t ss_off   = cnt_off + cnt_sz;
    const size_t ss_sz    = (size_t)(NSTREAM + 1) * 4;
    const size_t pl_off   = (ss_off + ss_sz + 15) & ~(size_t)15;
    const size_t base_need = pl_off + (size_t)KE * 8;
    const size_t xh_off   = (base_need + 63) & ~(size_t)63;
    const size_t full_need = xh_off + (size_t)N * F * 2;

    if (ws_size < base_need || lds_need > 64 * 1024) {
        hipMemsetAsync(out, 0, (size_t)out_size * sizeof(float), stream);
        gtconv_scatter<<<8192, 256, 0, stream>>>(x, h, vals, rows, cols, out, KE, E);
        return;
    }

    char* ws = (char*)d_ws;
    int*    cnt     = (int*)(ws + cnt_off);
    int*    ssBeg   = (int*)(ws + ss_off);
    int2*   payload = (int2*)(ws + pl_off);
    ushort* xh      = (ushort*)(ws + xh_off);
    const bool use_bf16 = (ws_size >= full_need);

    if (use_bf16) {
        const int n4 = (N * F) / 4;
        convert_kernel<<<(n4 + 255) / 256, 256, 0, stream>>>(x, xh, n4);
    }

    const int chunk = (KE + GWG - 1) / GWG;
    count_kernel<<<GWG, 1024, lds_need, stream>>>(rows, cnt, KE, NSTREAM, chunk);
    scan1_kernel<<<NSTREAM, GWG, 0, stream>>>(cnt, ssBeg);
    scan2_kernel<<<1, 1024, 0, stream>>>(ssBeg, NSTREAM);
    const int total = NSTREAM * GWG;
    scan3_kernel<<<(total + 1023) / 1024, 1024, 0, stream>>>(cnt, ssBeg, total);
    scatter_kernel<<<GWG, 1024, lds_need, stream>>>(rows, cols, vals, h, cnt,
                                                    payload, KE, E, K, NSTREAM, chunk);
    if (use_bf16)
        spmv_bf16_kernel<<<NB, 128, 0, stream>>>(ssBeg, payload, xh, out, N);
    else
        spmv_f32_kernel<<<NB, 128, 0, stream>>>(ssBeg, payload, x, out, N);
}